// Round 4
// baseline (16556.041 us; speedup 1.0000x reference)
//
#include <hip/hip_runtime.h>
#include <math.h>

#define DEV_INLINE __device__ __forceinline__

// TF32 rounding: round-to-nearest-even to 10-bit mantissa (19-bit total).
DEV_INLINE float tf32r(float x) {
  unsigned int u = __float_as_uint(x);
  unsigned int r = u + 0xFFFu + ((u >> 13) & 1u);
  r &= 0xFFFFE000u;
  return __uint_as_float(r);
}

// ---------------------------------------------------------------------------
// Quantization in f64: xd = clip(x*std + mean, 0, 1); q = trunc(xd*255)
// ---------------------------------------------------------------------------
DEV_INLINE int quantize_px(float v, double s, double m) {
  double xd = __dadd_rn(__dmul_rn((double)v, s), m);
  xd = fmin(fmax(xd, 0.0), 1.0);
  return (int)__dmul_rn(xd, 255.0);
}

// ---------------------------------------------------------------------------
// Co-occurrence: one thread per pixel, up to 4 global float atomics.
// ---------------------------------------------------------------------------
__global__ __launch_bounds__(256) void co_kernel(const float* __restrict__ x,
                                                 float* __restrict__ co) {
  int idx = blockIdx.x * 256 + threadIdx.x;   // 48*65536 threads
  int xw = idx & 255;
  int y  = (idx >> 8) & 255;
  int bc = idx >> 16;                          // b*3 + c
  int c  = bc % 3;
  double S = (c == 0) ? (double)0.229f : (c == 1) ? (double)0.224f : (double)0.225f;
  double M = (c == 0) ? (double)0.485f : (c == 1) ? (double)0.456f : (double)0.406f;
  const float* p = x + (size_t)bc * 65536;
  float* h = co + (size_t)bc * 65536;
  bool xr = xw < 255, yd = y < 255;
  int q00 = quantize_px(p[y * 256 + xw], S, M);
  int q01 = 0, q10 = 0, q11 = 0;
  if (xr)       q01 = quantize_px(p[y * 256 + xw + 1], S, M);
  if (yd)       q10 = quantize_px(p[(y + 1) * 256 + xw], S, M);
  if (xr && yd) q11 = quantize_px(p[(y + 1) * 256 + xw + 1], S, M);
  if (xr) atomicAdd(&h[q00 * 256 + q01], 1.f);
  if (yd) atomicAdd(&h[q00 * 256 + q10], 1.f);
  if (xr && yd) {
    atomicAdd(&h[q00 * 256 + q11], 1.f);
    atomicAdd(&h[q01 * 256 + q10], 1.f);
  }
}

// ---------------------------------------------------------------------------
// Conv — TF32-emulated: operands rounded to tf32 at LDS staging, f32 products
// and f32 accumulation (mimics GPU-default jax/cudnn conv precision).
// Block = 256 threads = one 16x16 output tile for one (b, co).
// ---------------------------------------------------------------------------
template <int K, int CIN, int COUT, int H, int W, bool RELU, bool POOL>
__global__ __launch_bounds__(256) void conv_tf32(
    const float* __restrict__ in, const float* __restrict__ wgt,
    const float* __restrict__ bias, float* __restrict__ out) {
  constexpr int PAD = K / 2;
  constexpr int IT = 16 + K - 1;
  constexpr int TILES_X = W / 16;

  __shared__ float s_in[IT][IT];
  __shared__ float s_w[CIN * K * K];
  __shared__ float s_out[16][16];

  const int t  = threadIdx.x;
  const int py = t >> 4, px = t & 15;
  const int by = blockIdx.x / TILES_X, bx = blockIdx.x % TILES_X;
  const int co = blockIdx.y;
  const int b  = blockIdx.z;

  for (int i = t; i < CIN * K * K; i += 256)
    s_w[i] = tf32r(wgt[(size_t)co * CIN * K * K + i]);

  const int y0g = by * 16 - PAD, x0g = bx * 16 - PAD;
  const float* inb = in + (size_t)b * CIN * H * W;

  float acc = 0.f;
  for (int ci = 0; ci < CIN; ++ci) {
    __syncthreads();
    for (int i = t; i < IT * IT; i += 256) {
      int rr = i / IT, cc = i % IT;
      int gy = y0g + rr, gx = x0g + cc;
      float v = 0.f;
      if (gy >= 0 && gy < H && gx >= 0 && gx < W)
        v = tf32r(inb[(size_t)ci * H * W + gy * W + gx]);
      s_in[rr][cc] = v;
    }
    __syncthreads();
#pragma unroll
    for (int ky = 0; ky < K; ++ky)
#pragma unroll
      for (int kx = 0; kx < K; ++kx)
        acc = fmaf(s_in[py + ky][px + kx], s_w[ci * K * K + ky * K + kx], acc);
  }

  if (POOL) {
    s_out[py][px] = acc;
    __syncthreads();
    if (t < 64) {
      constexpr int HO = H / 2, WO = W / 2;
      int qy = t >> 3, qx = t & 7;
      float m = fmaxf(fmaxf(s_out[2 * qy][2 * qx], s_out[2 * qy][2 * qx + 1]),
                      fmaxf(s_out[2 * qy + 1][2 * qx], s_out[2 * qy + 1][2 * qx + 1]));
      m += bias[co];
      out[((size_t)b * COUT + co) * HO * WO + (by * 8 + qy) * WO + (bx * 8 + qx)] = m;
    }
  } else {
    float v = acc + bias[co];
    if (RELU) v = fmaxf(v, 0.f);
    out[((size_t)b * COUT + co) * H * W + (by * 16 + py) * W + (bx * 16 + px)] = v;
  }
}

// ---------------------------------------------------------------------------
// FC1 — TF32 operands, f32 accumulation. One block per (o,b); 256 threads
// stride over k; LDS tree reduce.
// ---------------------------------------------------------------------------
__global__ __launch_bounds__(256) void fc1_tf32(const float* __restrict__ h,
                                                const float* __restrict__ w,
                                                float* __restrict__ f1) {
  const int o = blockIdx.x >> 4, b = blockIdx.x & 15;
  const int t = threadIdx.x;
  __shared__ float s[256];
  const float* hr = h + (size_t)b * 131072;
  const float* wr = w + (size_t)o * 131072;
  float acc = 0.f;
  for (int k = t; k < 131072; k += 256)
    acc = fmaf(tf32r(hr[k]), tf32r(wr[k]), acc);
  s[t] = acc;
  __syncthreads();
  for (int s2 = 128; s2 > 0; s2 >>= 1) {
    if (t < s2) s[t] += s[t + s2];
    __syncthreads();
  }
  if (t == 0) f1[b * 256 + o] = s[0];
}

__global__ void fc1_post(float* __restrict__ f1, const float* __restrict__ fb1) {
  int i = blockIdx.x * 256 + threadIdx.x;
  f1[i] = fmaxf(f1[i] + fb1[i & 255], 0.f);
}

__global__ void fc2_kernel(const float* __restrict__ f1,
                           const float* __restrict__ w,
                           const float* __restrict__ fb2,
                           float* __restrict__ f2) {
  int bb = blockIdx.x, o = threadIdx.x;
  __shared__ float s[256];
  s[o] = tf32r(f1[bb * 256 + o]);
  __syncthreads();
  const float* wr = w + (size_t)o * 256;
  float acc = 0.f;
#pragma unroll 8
  for (int k = 0; k < 256; ++k) acc = fmaf(tf32r(wr[k]), s[k], acc);
  f2[bb * 256 + o] = fmaxf(acc + fb2[o], 0.f);
}

__global__ void fc3_kernel(const float* __restrict__ f2,
                           const float* __restrict__ w,
                           const float* __restrict__ fb3,
                           float* __restrict__ out) {
  int bb = blockIdx.x, t = threadIdx.x;  // 64 threads = 1 wave
  float p = 0.f;
#pragma unroll
  for (int k = t; k < 256; k += 64)
    p = fmaf(tf32r(w[k]), tf32r(f2[bb * 256 + k]), p);
#pragma unroll
  for (int off = 32; off; off >>= 1) p += __shfl_down(p, off);
  if (t == 0) {
    double z = (double)p + (double)fb3[0];
    out[bb] = (float)(1.0 / (1.0 + exp(-z)));
  }
}

// ---------------------------------------------------------------------------
extern "C" void kernel_launch(void* const* d_in, const int* in_sizes, int n_in,
                              void* d_out, int out_size, void* d_ws,
                              size_t ws_size, hipStream_t stream) {
  const float* x   = (const float*)d_in[0];
  const float* w1  = (const float*)d_in[1];  const float* b1  = (const float*)d_in[2];
  const float* w2  = (const float*)d_in[3];  const float* b2  = (const float*)d_in[4];
  const float* w3  = (const float*)d_in[5];  const float* b3  = (const float*)d_in[6];
  const float* w4  = (const float*)d_in[7];  const float* b4  = (const float*)d_in[8];
  const float* w5  = (const float*)d_in[9];  const float* b5  = (const float*)d_in[10];
  const float* w6  = (const float*)d_in[11]; const float* b6  = (const float*)d_in[12];
  const float* fw1 = (const float*)d_in[13]; const float* fb1 = (const float*)d_in[14];
  const float* fw2 = (const float*)d_in[15]; const float* fb2 = (const float*)d_in[16];
  const float* fw3 = (const float*)d_in[17]; const float* fb3 = (const float*)d_in[18];
  float* outp = (float*)d_out;

  float* big    = (float*)d_ws;                // 33,554,432 floats (134 MB)
  float* small  = big + 33554432;              //  8,388,608 floats (33.5 MB)
  float* f1     = small + 8388608;             //  4096
  float* f2     = f1 + 4096;                   //  4096

  // co-occurrence (zero + scatter)
  hipMemsetAsync(small, 0, (size_t)16 * 3 * 65536 * sizeof(float), stream);
  co_kernel<<<12288, 256, 0, stream>>>(x, small);

  // convs (TF32-emulated)
  conv_tf32<3, 3, 32, 256, 256, true, false>
      <<<dim3(256, 32, 16), 256, 0, stream>>>(small, w1, b1, big);
  conv_tf32<5, 32, 32, 256, 256, false, true>
      <<<dim3(256, 32, 16), 256, 0, stream>>>(big, w2, b2, small);
  conv_tf32<3, 32, 64, 128, 128, true, false>
      <<<dim3(64, 64, 16), 256, 0, stream>>>(small, w3, b3, big);
  conv_tf32<5, 64, 64, 128, 128, false, true>
      <<<dim3(64, 64, 16), 256, 0, stream>>>(big, w4, b4, small);
  conv_tf32<3, 64, 128, 64, 64, true, false>
      <<<dim3(16, 128, 16), 256, 0, stream>>>(small, w5, b5, big);
  conv_tf32<5, 128, 128, 64, 64, false, true>
      <<<dim3(16, 128, 16), 256, 0, stream>>>(big, w6, b6, small);

  // fc head (TF32 operands)
  fc1_tf32<<<4096, 256, 0, stream>>>(small, fw1, f1);
  fc1_post<<<16, 256, 0, stream>>>(f1, fb1);
  fc2_kernel<<<16, 256, 0, stream>>>(f1, fw2, fb2, f2);
  fc3_kernel<<<16, 64, 0, stream>>>(f2, fw3, fb3, outp);
}

// Round 5
// 4321.222 us; speedup vs baseline: 3.8313x; 3.8313x over previous
//
#include <hip/hip_runtime.h>
#include <math.h>

#define DEV_INLINE __device__ __forceinline__

// TF32 rounding: RNE to 10-bit mantissa (matches ref's TF32-grade precision).
DEV_INLINE float tf32r(float x) {
  unsigned int u = __float_as_uint(x);
  unsigned int r = u + 0xFFFu + ((u >> 13) & 1u);
  r &= 0xFFFFE000u;
  return __uint_as_float(r);
}

// ---------------------------------------------------------------------------
// Quantization in f64: xd = clip(x*std + mean, 0, 1); q = trunc(xd*255)
// ---------------------------------------------------------------------------
DEV_INLINE int quantize_px(float v, double s, double m) {
  double xd = __dadd_rn(__dmul_rn((double)v, s), m);
  xd = fmin(fmax(xd, 0.0), 1.0);
  return (int)__dmul_rn(xd, 255.0);
}

// ---------------------------------------------------------------------------
// Co-occurrence: one thread per pixel, up to 4 global float atomics.
// ---------------------------------------------------------------------------
__global__ __launch_bounds__(256) void co_kernel(const float* __restrict__ x,
                                                 float* __restrict__ co) {
  int idx = blockIdx.x * 256 + threadIdx.x;   // 48*65536 threads
  int xw = idx & 255;
  int y  = (idx >> 8) & 255;
  int bc = idx >> 16;                          // b*3 + c
  int c  = bc % 3;
  double S = (c == 0) ? (double)0.229f : (c == 1) ? (double)0.224f : (double)0.225f;
  double M = (c == 0) ? (double)0.485f : (c == 1) ? (double)0.456f : (double)0.406f;
  const float* p = x + (size_t)bc * 65536;
  float* h = co + (size_t)bc * 65536;
  bool xr = xw < 255, yd = y < 255;
  int q00 = quantize_px(p[y * 256 + xw], S, M);
  int q01 = 0, q10 = 0, q11 = 0;
  if (xr)       q01 = quantize_px(p[y * 256 + xw + 1], S, M);
  if (yd)       q10 = quantize_px(p[(y + 1) * 256 + xw], S, M);
  if (xr && yd) q11 = quantize_px(p[(y + 1) * 256 + xw + 1], S, M);
  if (xr) atomicAdd(&h[q00 * 256 + q01], 1.f);
  if (yd) atomicAdd(&h[q00 * 256 + q10], 1.f);
  if (xr && yd) {
    atomicAdd(&h[q00 * 256 + q11], 1.f);
    atomicAdd(&h[q01 * 256 + q10], 1.f);
  }
}

// ---------------------------------------------------------------------------
// Conv, register-blocked (R1 structure, verified via R2/R3 bisect) with TF32
// operand rounding at LDS staging. Block: 16x16 px x 16 co; thread: 2x2 px
// x 4 co (16 f32 accumulators). Barriers per 8-ci chunk, not per ci.
// ---------------------------------------------------------------------------
template <int K, int CIN, int COUT, int H, int W, bool RELU, bool POOL>
__global__ __launch_bounds__(256, 2) void conv_fast(
    const float* __restrict__ in, const float* __restrict__ wgt,
    const float* __restrict__ bias, float* __restrict__ out) {
  constexpr int TH = 16, TW = 16, CO_BLK = 16;
  constexpr int CI_BLK = (CIN % 8 == 0) ? 8 : CIN;
  constexpr int PAD = K / 2;
  constexpr int IR = TH + K - 1, IC = TW + K - 1, ICP = IC + 1;
  constexpr int TILES_X = W / TW;

  __shared__ float s_in[CI_BLK][IR][ICP];
  __shared__ float s_w[CO_BLK][CI_BLK][K * K];

  const int t = threadIdx.x;
  const int by = blockIdx.x / TILES_X, bx = blockIdx.x % TILES_X;
  const int co_base = blockIdx.y * CO_BLK;
  const int b = blockIdx.z;

  const int cog = t >> 6;          // 0..3 (wave-uniform -> s_w broadcast)
  const int pg = t & 63;
  const int py0 = (pg >> 3) * 2;   // 0,2,..,14
  const int px0 = (pg & 7) * 2;    // 0,2,..,14

  float acc[2][2][4];
#pragma unroll
  for (int i = 0; i < 2; ++i)
#pragma unroll
    for (int j = 0; j < 2; ++j)
#pragma unroll
      for (int k = 0; k < 4; ++k) acc[i][j][k] = 0.f;

  const int y0g = by * TH - PAD, x0g = bx * TW - PAD;
  const float* inb = in + (size_t)b * CIN * H * W;

  for (int ci0 = 0; ci0 < CIN; ci0 += CI_BLK) {
    // stage input tile (tf32-rounded)
    for (int i = t; i < CI_BLK * IR * IC; i += 256) {
      int ci = i / (IR * IC), rem = i % (IR * IC);
      int rr = rem / IC, cc = rem % IC;
      int gy = y0g + rr, gx = x0g + cc;
      float v = 0.f;
      if (gy >= 0 && gy < H && gx >= 0 && gx < W)
        v = tf32r(inb[(size_t)(ci0 + ci) * H * W + gy * W + gx]);
      s_in[ci][rr][cc] = v;
    }
    // stage weights (tf32-rounded)
    for (int i = t; i < CO_BLK * CI_BLK * K * K; i += 256) {
      int co = i / (CI_BLK * K * K), rem = i % (CI_BLK * K * K);
      int ci = rem / (K * K), kk = rem % (K * K);
      s_w[co][ci][kk] =
          tf32r(wgt[((size_t)(co_base + co) * CIN + (ci0 + ci)) * K * K + kk]);
    }
    __syncthreads();

#pragma unroll 1
    for (int ci = 0; ci < CI_BLK; ++ci) {
#pragma unroll
      for (int ky = 0; ky < K; ++ky) {
        float wr[4][K];
#pragma unroll
        for (int co = 0; co < 4; ++co)
#pragma unroll
          for (int kx = 0; kx < K; ++kx)
            wr[co][kx] = s_w[cog * 4 + co][ci][ky * K + kx];
#pragma unroll
        for (int py = 0; py < 2; ++py) {
          float r[K + 1];
#pragma unroll
          for (int j = 0; j < K + 1; ++j)
            r[j] = s_in[ci][py0 + py + ky][px0 + j];
#pragma unroll
          for (int kx = 0; kx < K; ++kx)
#pragma unroll
            for (int px = 0; px < 2; ++px)
#pragma unroll
              for (int co = 0; co < 4; ++co)
                acc[py][px][co] = fmaf(r[px + kx], wr[co][kx], acc[py][px][co]);
        }
      }
    }
    __syncthreads();
  }

  // epilogue (f32)
  if (POOL) {
    constexpr int HO = H / 2, WO = W / 2;
    int oy = by * (TH / 2) + (pg >> 3), ox = bx * (TW / 2) + (pg & 7);
#pragma unroll
    for (int co = 0; co < 4; ++co) {
      int cg = co_base + cog * 4 + co;
      float v = fmaxf(fmaxf(acc[0][0][co], acc[0][1][co]),
                      fmaxf(acc[1][0][co], acc[1][1][co]));
      v += bias[cg];
      out[((size_t)b * COUT + cg) * HO * WO + oy * WO + ox] = v;
    }
  } else {
#pragma unroll
    for (int co = 0; co < 4; ++co) {
      int cg = co_base + cog * 4 + co;
      float bv = bias[cg];
#pragma unroll
      for (int py = 0; py < 2; ++py) {
        float2 v;
        v.x = acc[py][0][co] + bv;
        v.y = acc[py][1][co] + bv;
        if (RELU) { v.x = fmaxf(v.x, 0.f); v.y = fmaxf(v.y, 0.f); }
        *(float2*)&out[((size_t)b * COUT + cg) * H * W +
                       (by * TH + py0 + py) * W + (bx * TW + px0)] = v;
      }
    }
  }
}

// ---------------------------------------------------------------------------
// FC1 — TF32 operands, f32 accumulation. One block per (o,b); 256 threads
// stride over k; LDS tree reduce. (Unchanged from R4.)
// ---------------------------------------------------------------------------
__global__ __launch_bounds__(256) void fc1_tf32(const float* __restrict__ h,
                                                const float* __restrict__ w,
                                                float* __restrict__ f1) {
  const int o = blockIdx.x >> 4, b = blockIdx.x & 15;
  const int t = threadIdx.x;
  __shared__ float s[256];
  const float* hr = h + (size_t)b * 131072;
  const float* wr = w + (size_t)o * 131072;
  float acc = 0.f;
  for (int k = t; k < 131072; k += 256)
    acc = fmaf(tf32r(hr[k]), tf32r(wr[k]), acc);
  s[t] = acc;
  __syncthreads();
  for (int s2 = 128; s2 > 0; s2 >>= 1) {
    if (t < s2) s[t] += s[t + s2];
    __syncthreads();
  }
  if (t == 0) f1[b * 256 + o] = s[0];
}

__global__ void fc1_post(float* __restrict__ f1, const float* __restrict__ fb1) {
  int i = blockIdx.x * 256 + threadIdx.x;
  f1[i] = fmaxf(f1[i] + fb1[i & 255], 0.f);
}

__global__ void fc2_kernel(const float* __restrict__ f1,
                           const float* __restrict__ w,
                           const float* __restrict__ fb2,
                           float* __restrict__ f2) {
  int bb = blockIdx.x, o = threadIdx.x;
  __shared__ float s[256];
  s[o] = tf32r(f1[bb * 256 + o]);
  __syncthreads();
  const float* wr = w + (size_t)o * 256;
  float acc = 0.f;
#pragma unroll 8
  for (int k = 0; k < 256; ++k) acc = fmaf(tf32r(wr[k]), s[k], acc);
  f2[bb * 256 + o] = fmaxf(acc + fb2[o], 0.f);
}

__global__ void fc3_kernel(const float* __restrict__ f2,
                           const float* __restrict__ w,
                           const float* __restrict__ fb3,
                           float* __restrict__ out) {
  int bb = blockIdx.x, t = threadIdx.x;  // 64 threads = 1 wave
  float p = 0.f;
#pragma unroll
  for (int k = t; k < 256; k += 64)
    p = fmaf(tf32r(w[k]), tf32r(f2[bb * 256 + k]), p);
#pragma unroll
  for (int off = 32; off; off >>= 1) p += __shfl_down(p, off);
  if (t == 0) {
    double z = (double)p + (double)fb3[0];
    out[bb] = (float)(1.0 / (1.0 + exp(-z)));
  }
}

// ---------------------------------------------------------------------------
extern "C" void kernel_launch(void* const* d_in, const int* in_sizes, int n_in,
                              void* d_out, int out_size, void* d_ws,
                              size_t ws_size, hipStream_t stream) {
  const float* x   = (const float*)d_in[0];
  const float* w1  = (const float*)d_in[1];  const float* b1  = (const float*)d_in[2];
  const float* w2  = (const float*)d_in[3];  const float* b2  = (const float*)d_in[4];
  const float* w3  = (const float*)d_in[5];  const float* b3  = (const float*)d_in[6];
  const float* w4  = (const float*)d_in[7];  const float* b4  = (const float*)d_in[8];
  const float* w5  = (const float*)d_in[9];  const float* b5  = (const float*)d_in[10];
  const float* w6  = (const float*)d_in[11]; const float* b6  = (const float*)d_in[12];
  const float* fw1 = (const float*)d_in[13]; const float* fb1 = (const float*)d_in[14];
  const float* fw2 = (const float*)d_in[15]; const float* fb2 = (const float*)d_in[16];
  const float* fw3 = (const float*)d_in[17]; const float* fb3 = (const float*)d_in[18];
  float* outp = (float*)d_out;

  float* big    = (float*)d_ws;                // 33,554,432 floats (134 MB)
  float* small  = big + 33554432;              //  8,388,608 floats (33.5 MB)
  float* f1     = small + 8388608;             //  4096
  float* f2     = f1 + 4096;                   //  4096

  // co-occurrence (zero + scatter)
  hipMemsetAsync(small, 0, (size_t)16 * 3 * 65536 * sizeof(float), stream);
  co_kernel<<<12288, 256, 0, stream>>>(x, small);

  // convs (register-blocked, TF32-emulated)
  conv_fast<3, 3, 32, 256, 256, true, false>
      <<<dim3(256, 2, 16), 256, 0, stream>>>(small, w1, b1, big);
  conv_fast<5, 32, 32, 256, 256, false, true>
      <<<dim3(256, 2, 16), 256, 0, stream>>>(big, w2, b2, small);
  conv_fast<3, 32, 64, 128, 128, true, false>
      <<<dim3(64, 4, 16), 256, 0, stream>>>(small, w3, b3, big);
  conv_fast<5, 64, 64, 128, 128, false, true>
      <<<dim3(64, 4, 16), 256, 0, stream>>>(big, w4, b4, small);
  conv_fast<3, 64, 128, 64, 64, true, false>
      <<<dim3(16, 8, 16), 256, 0, stream>>>(small, w5, b5, big);
  conv_fast<5, 128, 128, 64, 64, false, true>
      <<<dim3(16, 8, 16), 256, 0, stream>>>(big, w6, b6, small);

  // fc head (TF32 operands)
  fc1_tf32<<<4096, 256, 0, stream>>>(small, fw1, f1);
  fc1_post<<<16, 256, 0, stream>>>(f1, fb1);
  fc2_kernel<<<16, 256, 0, stream>>>(f1, fw2, fb2, f2);
  fc3_kernel<<<16, 64, 0, stream>>>(f2, fw3, fb3, outp);
}